// Round 2
// baseline (3836.908 us; speedup 1.0000x reference)
//
#include <hip/hip_runtime.h>
#include <math.h>

// Program interpreter: B=1M rows, 19 steps of MLP(2->64->64->3) + argmax walk.
// All inputs/outputs are fp32 (reference is jnp.float32 end-to-end).
// One thread per row; weights are wave-uniform -> expect s_load + v_fmac v,s,v.

#define NSTEPS 19

__global__ __launch_bounds__(256)
void program_kernel(const float* __restrict__ x,
                    const float* __restrict__ W1,
                    const float* __restrict__ b1,
                    const float* __restrict__ W2,
                    const float* __restrict__ b2,
                    const float* __restrict__ W3,
                    const float* __restrict__ b3,
                    float* __restrict__ out,
                    int B) {
    const int row = threadIdx.x + blockIdx.x * blockDim.x;
    if (row >= B) return;

    // x row = 6 floats: [pos, fwd, p0, p1, p2, step]
    const float2* __restrict__ xr = (const float2*)x;
    const float2 a = xr[row * 3 + 0];
    const float2 c = xr[row * 3 + 2];
    float pos = a.x;     // col 0: position
    float fwd = a.y;     // col 1: forward counter
    const float c5 = c.y;  // col 5: step counter (0)

    float l0 = 0.f, l1 = 0.f, l2 = 0.f;

    #pragma unroll 1
    for (int t = 0; t < NSTEPS; ++t) {
        // layer 1: h1 = relu([pos,fwd] @ W1 + b1); W1 row-major (2,64)
        float h1[64];
        #pragma unroll
        for (int j = 0; j < 64; ++j) {
            h1[j] = fmaxf(0.f, fmaf(pos, W1[j], fmaf(fwd, W1[64 + j], b1[j])));
        }
        // layers 2+3 fused: h2 in 4 chunks of 16 columns, folded into logits.
        l0 = b3[0]; l1 = b3[1]; l2 = b3[2];
        #pragma unroll
        for (int jc = 0; jc < 4; ++jc) {
            float acc[16];
            #pragma unroll
            for (int j = 0; j < 16; ++j) acc[j] = b2[jc * 16 + j];
            #pragma unroll 4
            for (int k = 0; k < 64; ++k) {
                const float hk = h1[k];
                const float* __restrict__ w2row = W2 + k * 64 + jc * 16;
                #pragma unroll
                for (int j = 0; j < 16; ++j)
                    acc[j] = fmaf(hk, w2row[j], acc[j]);
            }
            #pragma unroll
            for (int j = 0; j < 16; ++j) {
                const float h = fmaxf(0.f, acc[j]);
                const int jj = jc * 16 + j;
                l0 = fmaf(h, W3[jj * 3 + 0], l0);
                l1 = fmaf(h, W3[jj * 3 + 1], l1);
                l2 = fmaf(h, W3[jj * 3 + 2], l2);
            }
        }
        // argmax over (l0,l1,l2), first-max-wins (jnp.argmax semantics);
        // sigmoid is monotone so argmax on logits == argmax on probs.
        int idx = 0;
        float best = l0;
        if (l1 > best) { best = l1; idx = 1; }
        if (l2 > best) { idx = 2; }
        pos += (float)(idx - 1);   // up=-1, right=0, down=+1
        fwd += 1.0f;
    }

    // final probs from last iteration's logits
    const float p0 = 1.f / (1.f + __expf(-l0));
    const float p1 = 1.f / (1.f + __expf(-l1));
    const float p2 = 1.f / (1.f + __expf(-l2));
    const float o5 = c5 + (float)NSTEPS;

    float2* __restrict__ outr = (float2*)out + row * 3;
    outr[0] = make_float2(pos, fwd);
    outr[1] = make_float2(p0, p1);
    outr[2] = make_float2(p2, o5);
}

extern "C" void kernel_launch(void* const* d_in, const int* in_sizes, int n_in,
                              void* d_out, int out_size, void* d_ws, size_t ws_size,
                              hipStream_t stream) {
    const float* x  = (const float*)d_in[0];
    const float* W1 = (const float*)d_in[1];
    const float* b1 = (const float*)d_in[2];
    const float* W2 = (const float*)d_in[3];
    const float* b2 = (const float*)d_in[4];
    const float* W3 = (const float*)d_in[5];
    const float* b3 = (const float*)d_in[6];
    float* out = (float*)d_out;

    const int B = in_sizes[0] / 6;

    program_kernel<<<(B + 255) / 256, 256, 0, stream>>>(
        x, W1, b1, W2, b2, W3, b3, out, B);
}

// Round 3
// 1790.638 us; speedup vs baseline: 2.1428x; 2.1428x over previous
//
#include <hip/hip_runtime.h>
#include <math.h>

// Program interpreter: B=1M rows, 19 steps of MLP(2->64->64->3) + argmax walk.
// All fp32. One thread per row.
//
// R2 post-mortem: `#pragma unroll 4` left h1[k] dynamically indexed -> h1[64]
// demoted to scratch -> 4.9 GB spill writes + 9.2 GB reads (WRITE_SIZE matched
// 1M*19*256B exactly). This version has NO hidden-layer array: layer-1 output
// hk is computed inline in the k-loop and folded immediately into 64 layer-2
// accumulators acc[64], which are only ever indexed by fully-unrolled static j.
// k appears only in wave-uniform load addresses (s_load + v_fmac v,s,v).

#define NSTEPS 19

__global__ __launch_bounds__(256)
void program_kernel(const float* __restrict__ x,
                    const float* __restrict__ W1,
                    const float* __restrict__ b1,
                    const float* __restrict__ W2,
                    const float* __restrict__ b2,
                    const float* __restrict__ W3,
                    const float* __restrict__ b3,
                    float* __restrict__ out,
                    int B) {
    const int row = threadIdx.x + blockIdx.x * blockDim.x;
    if (row >= B) return;

    // x row = 6 floats: [pos, fwd, p0, p1, p2, step]
    const float2* __restrict__ xr = (const float2*)x;
    const float2 a = xr[row * 3 + 0];
    const float2 c = xr[row * 3 + 2];
    float pos = a.x;       // col 0: position
    float fwd = a.y;       // col 1: forward counter
    const float c5 = c.y;  // col 5: step counter (0)

    float l0 = 0.f, l1 = 0.f, l2 = 0.f;
    float acc[64];  // layer-2 accumulators — static indices only -> VGPRs

    #pragma unroll 1
    for (int t = 0; t < NSTEPS; ++t) {
        #pragma unroll
        for (int j = 0; j < 64; ++j) acc[j] = b2[j];

        // layers 1+2 fused: hk consumed the cycle it's produced.
        // Per-column sum order (k ascending) identical to R2 -> same fp result.
        #pragma unroll 4
        for (int k = 0; k < 64; ++k) {
            const float hk =
                fmaxf(0.f, fmaf(pos, W1[k], fmaf(fwd, W1[64 + k], b1[k])));
            const float* __restrict__ w2row = W2 + k * 64;
            #pragma unroll
            for (int j = 0; j < 64; ++j)
                acc[j] = fmaf(hk, w2row[j], acc[j]);
        }

        // layer 3: fold relu(acc[j]) into the 3 logits, j ascending (as R2).
        l0 = b3[0]; l1 = b3[1]; l2 = b3[2];
        #pragma unroll
        for (int j = 0; j < 64; ++j) {
            const float h = fmaxf(0.f, acc[j]);
            l0 = fmaf(h, W3[j * 3 + 0], l0);
            l1 = fmaf(h, W3[j * 3 + 1], l1);
            l2 = fmaf(h, W3[j * 3 + 2], l2);
        }

        // argmax over (l0,l1,l2), first-max-wins (jnp.argmax semantics);
        // sigmoid is monotone so argmax on logits == argmax on probs.
        int idx = 0;
        float best = l0;
        if (l1 > best) { best = l1; idx = 1; }
        if (l2 > best) { idx = 2; }
        pos += (float)(idx - 1);   // up=-1, right=0, down=+1
        fwd += 1.0f;
    }

    // final probs from last iteration's logits
    const float p0 = 1.f / (1.f + __expf(-l0));
    const float p1 = 1.f / (1.f + __expf(-l1));
    const float p2 = 1.f / (1.f + __expf(-l2));
    const float o5 = c5 + (float)NSTEPS;

    float2* __restrict__ outr = (float2*)out + row * 3;
    outr[0] = make_float2(pos, fwd);
    outr[1] = make_float2(p0, p1);
    outr[2] = make_float2(p2, o5);
}

extern "C" void kernel_launch(void* const* d_in, const int* in_sizes, int n_in,
                              void* d_out, int out_size, void* d_ws, size_t ws_size,
                              hipStream_t stream) {
    const float* x  = (const float*)d_in[0];
    const float* W1 = (const float*)d_in[1];
    const float* b1 = (const float*)d_in[2];
    const float* W2 = (const float*)d_in[3];
    const float* b2 = (const float*)d_in[4];
    const float* W3 = (const float*)d_in[5];
    const float* b3 = (const float*)d_in[6];
    float* out = (float*)d_out;

    const int B = in_sizes[0] / 6;

    program_kernel<<<(B + 255) / 256, 256, 0, stream>>>(
        x, W1, b1, W2, b2, W3, b3, out, B);
}

// Round 4
// 852.263 us; speedup vs baseline: 4.5020x; 2.1010x over previous
//
#include <hip/hip_runtime.h>
#include <math.h>

// Program interpreter: B=1M rows, 19 steps of MLP(2->64->64->3) + argmax walk.
// fp32 emulated on f16 MFMA via 2-limb splits (lo limb scaled 2^12 to stay
// normal). Wave = 16 rows (MFMA M); lanes 4x-replicate row state.
//  - A-frag (16x16x32): lane holds A[m=lane&15][k=(lane>>4)*8+j], j=0..7
//  - B-frag:            lane holds B[k=(lane>>4)*8+j][n=lane&15]
//  - C-frag:            lane holds D[row=4*(lane>>4)+reg][col=16t+(lane&15)]
// Layer-3 reduced across the 16 lanes of each quad-group via DPP butterfly.
// No LDS allocation, no __syncthreads; waves fully independent.

#define NSTEPS 19

typedef _Float16 half8 __attribute__((ext_vector_type(8)));
typedef float float4v __attribute__((ext_vector_type(4)));

template <int CTRL>
__device__ __forceinline__ float dpp_add(float v) {
    int p = __builtin_amdgcn_update_dpp(0, __builtin_bit_cast(int, v),
                                        CTRL, 0xF, 0xF, true);
    return v + __builtin_bit_cast(float, p);
}

// sum across the 16-lane DPP row (stays within each lane-group of 16)
__device__ __forceinline__ float reduce16(float v) {
    v = dpp_add<0xB1>(v);   // quad_perm [1,0,3,2]  : xor 1
    v = dpp_add<0x4E>(v);   // quad_perm [2,3,0,1]  : xor 2
    v = dpp_add<0x141>(v);  // row_half_mirror      : cross quads within 8
    v = dpp_add<0x140>(v);  // row_mirror           : cross 8-halves within 16
    return v;
}

__global__ __launch_bounds__(256, 2)
void program_kernel(const float* __restrict__ x,
                    const float* __restrict__ W1,
                    const float* __restrict__ b1,
                    const float* __restrict__ W2,
                    const float* __restrict__ b2,
                    const float* __restrict__ W3,
                    const float* __restrict__ b3,
                    float* __restrict__ out,
                    int B) {
    const int tid    = threadIdx.x;
    const int lane   = tid & 63;
    const int wave   = tid >> 6;
    const int lanelo = lane & 15;   // m: my row within the wave tile; C col idx
    const int q8     = lane >> 4;   // quad-group 0..3
    const int rowBase = blockIdx.x * 64 + wave * 16;
    const int myRow   = rowBase + lanelo;
    const int rowLd   = myRow < B ? myRow : (B - 1);   // clamped for loads

    // ---- one-time per-lane constants ----
    // W1/b1 slices for my k set: k = q8*8+j (kf=0) and 32+q8*8+j (kf=1)
    float w1r0[16], w1r1[16], b1v[16];
    {
        const int k0 = q8 * 8;
        #pragma unroll
        for (int j = 0; j < 8; ++j) {
            w1r0[j]     = W1[k0 + j];
            w1r0[8 + j] = W1[32 + k0 + j];
            w1r1[j]     = W1[64 + k0 + j];
            w1r1[8 + j] = W1[96 + k0 + j];
            b1v[j]      = b1[k0 + j];
            b1v[8 + j]  = b1[32 + k0 + j];
        }
    }
    // W3/b2 per-lane: cols c = 16t + lanelo
    float w3v[4][3], b2v[4];
    #pragma unroll
    for (int t = 0; t < 4; ++t) {
        const int c = t * 16 + lanelo;
        w3v[t][0] = W3[c * 3 + 0];
        w3v[t][1] = W3[c * 3 + 1];
        w3v[t][2] = W3[c * 3 + 2];
        b2v[t]    = b2[c];
    }
    const float b3v0 = b3[0], b3v1 = b3[1], b3v2 = b3[2];

    // W2 B-fragments, f16 2-limb (lo limb scaled by 2^12)
    half8 Bh[2][4], Bl[2][4];
    #pragma unroll
    for (int kf = 0; kf < 2; ++kf) {
        #pragma unroll
        for (int t = 0; t < 4; ++t) {
            half8 bh, bl;
            #pragma unroll
            for (int j = 0; j < 8; ++j) {
                const float w  = W2[(kf * 32 + q8 * 8 + j) * 64 + t * 16 + lanelo];
                const _Float16 wh = (_Float16)w;
                const _Float16 wl = (_Float16)((w - (float)wh) * 4096.0f);
                bh[j] = wh;
                bl[j] = wl;
            }
            Bh[kf][t] = bh;
            Bl[kf][t] = bl;
        }
    }

    // initial row state (4x replicated across lane groups)
    float pos, fwd, c5;
    {
        const float* xr = x + (size_t)rowLd * 6;
        pos = xr[0];
        fwd = xr[1];
        c5  = xr[5];
    }

    const int srcLane = (lanelo >> 2) * 16;  // a lane of the group owning my row
    const int selq    = lanelo & 3;          // which reg slot holds my row there

    float l0q[4], l1q[4], l2q[4];

    #pragma unroll 1
    for (int step = 0; step < NSTEPS; ++step) {
        // ---- layer 1 + f16 2-limb split into A-fragments ----
        half8 Ah[2], Al[2];
        #pragma unroll
        for (int kf = 0; kf < 2; ++kf) {
            half8 ah, al;
            #pragma unroll
            for (int j = 0; j < 8; ++j) {
                const int e = kf * 8 + j;
                const float h =
                    fmaxf(0.f, fmaf(pos, w1r0[e], fmaf(fwd, w1r1[e], b1v[e])));
                const _Float16 hh = (_Float16)h;
                const _Float16 hl = (_Float16)((h - (float)hh) * 4096.0f);
                ah[j] = hh;
                al[j] = hl;
            }
            Ah[kf] = ah;
            Al[kf] = al;
        }

        // ---- layer 2 via MFMA: accA = b2 + hh*wh ; accB = hh*wl' + hl'*wh ----
        float4v accA[4], accB[4];
        #pragma unroll
        for (int t = 0; t < 4; ++t) {
            accA[t] = (float4v){b2v[t], b2v[t], b2v[t], b2v[t]};
            accB[t] = (float4v){0.f, 0.f, 0.f, 0.f};
        }
        #pragma unroll
        for (int t = 0; t < 4; ++t) {
            #pragma unroll
            for (int kf = 0; kf < 2; ++kf) {
                accB[t] = __builtin_amdgcn_mfma_f32_16x16x32_f16(
                    Ah[kf], Bl[kf][t], accB[t], 0, 0, 0);
                accB[t] = __builtin_amdgcn_mfma_f32_16x16x32_f16(
                    Al[kf], Bh[kf][t], accB[t], 0, 0, 0);
                accA[t] = __builtin_amdgcn_mfma_f32_16x16x32_f16(
                    Ah[kf], Bh[kf][t], accA[t], 0, 0, 0);
            }
        }

        // ---- layer 3: per-lane partials, DPP reduce over 16-lane group ----
        #pragma unroll
        for (int q = 0; q < 4; ++q) {
            float s0 = 0.f, s1 = 0.f, s2 = 0.f;
            #pragma unroll
            for (int t = 0; t < 4; ++t) {
                const float h2 =
                    fmaxf(0.f, fmaf(accB[t][q], 1.0f / 4096.0f, accA[t][q]));
                s0 = fmaf(h2, w3v[t][0], s0);
                s1 = fmaf(h2, w3v[t][1], s1);
                s2 = fmaf(h2, w3v[t][2], s2);
            }
            l0q[q] = reduce16(s0) + b3v0;
            l1q[q] = reduce16(s1) + b3v1;
            l2q[q] = reduce16(s2) + b3v2;
        }

        // ---- argmax (first-max-wins) per reg slot; sigmoid is monotone ----
        float dq[4];
        #pragma unroll
        for (int q = 0; q < 4; ++q) {
            const float a0 = l0q[q], a1 = l1q[q], a2 = l2q[q];
            const float m01 = fmaxf(a0, a1);
            dq[q] = (a2 > m01) ? 1.0f : ((a1 > a0) ? 0.0f : -1.0f);
        }

        // ---- route my row's delta back to its owner lanes ----
        const float r0 = __shfl(dq[0], srcLane);
        const float r1 = __shfl(dq[1], srcLane);
        const float r2 = __shfl(dq[2], srcLane);
        const float r3 = __shfl(dq[3], srcLane);
        const float dsel = (selq & 2) ? ((selq & 1) ? r3 : r2)
                                      : ((selq & 1) ? r1 : r0);
        pos += dsel;
        fwd += 1.0f;
    }

    // ---- route final logits to owner lanes, sigmoid, store ----
    float fl0, fl1, fl2;
    {
        float t0[4], t1[4], t2[4];
        #pragma unroll
        for (int q = 0; q < 4; ++q) {
            t0[q] = __shfl(l0q[q], srcLane);
            t1[q] = __shfl(l1q[q], srcLane);
            t2[q] = __shfl(l2q[q], srcLane);
        }
        fl0 = (selq & 2) ? ((selq & 1) ? t0[3] : t0[2])
                         : ((selq & 1) ? t0[1] : t0[0]);
        fl1 = (selq & 2) ? ((selq & 1) ? t1[3] : t1[2])
                         : ((selq & 1) ? t1[1] : t1[0]);
        fl2 = (selq & 2) ? ((selq & 1) ? t2[3] : t2[2])
                         : ((selq & 1) ? t2[1] : t2[0]);
    }

    if (q8 == 0 && myRow < B) {
        const float p0 = 1.f / (1.f + __expf(-fl0));
        const float p1 = 1.f / (1.f + __expf(-fl1));
        const float p2 = 1.f / (1.f + __expf(-fl2));
        float2* o = (float2*)(out + (size_t)myRow * 6);
        o[0] = make_float2(pos, fwd);
        o[1] = make_float2(p0, p1);
        o[2] = make_float2(p2, c5 + (float)NSTEPS);
    }
}

extern "C" void kernel_launch(void* const* d_in, const int* in_sizes, int n_in,
                              void* d_out, int out_size, void* d_ws, size_t ws_size,
                              hipStream_t stream) {
    const float* x  = (const float*)d_in[0];
    const float* W1 = (const float*)d_in[1];
    const float* b1 = (const float*)d_in[2];
    const float* W2 = (const float*)d_in[3];
    const float* b2 = (const float*)d_in[4];
    const float* W3 = (const float*)d_in[5];
    const float* b3 = (const float*)d_in[6];
    float* out = (float*)d_out;

    const int B = in_sizes[0] / 6;              // 1048576
    const int nBlocks = (B + 63) / 64;          // 64 rows per block (4 waves x 16)

    program_kernel<<<nBlocks, 256, 0, stream>>>(
        x, W1, b1, W2, b2, W3, b3, out, B);
}

// Round 6
// 686.159 us; speedup vs baseline: 5.5919x; 1.2421x over previous
//
#include <hip/hip_runtime.h>
#include <math.h>

// Program interpreter: B=1M rows, 19 steps of MLP(2->64->64->3) + argmax walk.
// fp32 emulated on f16 MFMA, 2-limb splits (lo limb scaled 2^12, RTZ pack).
//
// R6 = R5 + fix: cvt_pkrtz returns __fp16x2 -> bit_cast to half2v.
// Swapped-operand MFMA — A = W2^T limb frags (static), B = h1^T limbs.
// 16x16x32 f16 MFMA, D[row=n][col=m]: each lane owns row m=lane&15 entirely,
// holding h2 at n = 16t + 4*(lane>>4) + reg. Layer-3 partials are per-lane;
// full logits = 2-stage cross-replica reduce (xor16 swizzle + xor32 shfl),
// after which ALL lanes have their row's logits -> argmax/update need no
// routing. accA's first MFMA uses a persistent b2-broadcast C fragment; accB's
// uses a zero frag -> no per-step accumulator init instructions.

#define NSTEPS 19

typedef _Float16 half8 __attribute__((ext_vector_type(8)));
typedef _Float16 half2v __attribute__((ext_vector_type(2)));
typedef float float4v __attribute__((ext_vector_type(4)));

__device__ __forceinline__ half2v pkrtz(float a, float b) {
    return __builtin_bit_cast(half2v, __builtin_amdgcn_cvt_pkrtz(a, b));
}

__device__ __forceinline__ float swz_xor16(float v) {
    // BitMode: and=0x1F, or=0, xor=16 -> lane' = lane ^ 16 (within 32-group)
    int r = __builtin_amdgcn_ds_swizzle(__builtin_bit_cast(int, v), 0x401F);
    return __builtin_bit_cast(float, r);
}

__global__ __launch_bounds__(256, 2)
void program_kernel(const float* __restrict__ x,
                    const float* __restrict__ W1,
                    const float* __restrict__ b1,
                    const float* __restrict__ W2,
                    const float* __restrict__ b2,
                    const float* __restrict__ W3,
                    const float* __restrict__ b3,
                    float* __restrict__ out,
                    int B) {
    const int tid    = threadIdx.x;
    const int lane   = tid & 63;
    const int wave   = tid >> 6;
    const int lanelo = lane & 15;   // m: my batch row within the wave tile
    const int q8     = lane >> 4;   // replica / k-group 0..3
    const int rowBase = blockIdx.x * 64 + wave * 16;
    const int myRow   = rowBase + lanelo;
    const int rowLd   = myRow < B ? myRow : (B - 1);

    // ---- W1/b1 slices: element e (0..15) <-> k = (e<8?0:32) + q8*8 + (e&7)
    float w1a[16], w1b[16], b1v[16];
    #pragma unroll
    for (int j = 0; j < 8; ++j) {
        const int k0 = q8 * 8 + j;
        w1a[j]     = W1[k0];
        w1a[8 + j] = W1[32 + k0];
        w1b[j]     = W1[64 + k0];
        w1b[8 + j] = W1[96 + k0];
        b1v[j]     = b1[k0];
        b1v[8 + j] = b1[32 + k0];
    }

    // ---- W2^T limb A-frags: lane holds A[m=lanelo][k=q8*8+j] for n-tile t:
    //      Wh/Wl[kf][t][j] = limbs of W2[(kf*32 + q8*8 + j)][16t + lanelo]
    half8 Wh[2][4], Wl[2][4];
    #pragma unroll
    for (int kf = 0; kf < 2; ++kf) {
        #pragma unroll
        for (int t = 0; t < 4; ++t) {
            half8 bh, bl;
            #pragma unroll
            for (int j = 0; j < 8; ++j) {
                const float w =
                    W2[(kf * 32 + q8 * 8 + j) * 64 + t * 16 + lanelo];
                const _Float16 wh = (_Float16)w;                       // RNE
                const _Float16 wl = (_Float16)((w - (float)wh) * 4096.0f);
                bh[j] = wh;
                bl[j] = wl;
            }
            Wh[kf][t] = bh;
            Wl[kf][t] = bl;
        }
    }

    // ---- b2 C-init frags and W3 coefs for this lane's n-set: n=16t+4*q8+r
    float4v b2f[4];
    float w3v[4][4][3];
    #pragma unroll
    for (int t = 0; t < 4; ++t) {
        #pragma unroll
        for (int r = 0; r < 4; ++r) {
            const int n = t * 16 + q8 * 4 + r;
            b2f[t][r]    = b2[n];
            w3v[t][r][0] = W3[n * 3 + 0];
            w3v[t][r][1] = W3[n * 3 + 1];
            w3v[t][r][2] = W3[n * 3 + 2];
        }
    }
    const float b3v0 = b3[0], b3v1 = b3[1], b3v2 = b3[2];

    // ---- initial row state (4x replicated across q8 groups)
    float pos, fwd, c5;
    {
        const float* xr = x + (size_t)rowLd * 6;
        pos = xr[0];
        fwd = xr[1];
        c5  = xr[5];
    }

    const float4v zf = {0.f, 0.f, 0.f, 0.f};
    float l0 = 0.f, l1 = 0.f, l2 = 0.f;

    #pragma unroll 1
    for (int step = 0; step < NSTEPS; ++step) {
        // ---- layer 1 -> B-frag limbs (row lanelo, k = kf*32 + q8*8 + j) ----
        half8 Hh[2], Hl[2];
        #pragma unroll
        for (int kf = 0; kf < 2; ++kf) {
            float h[8];
            #pragma unroll
            for (int j = 0; j < 8; ++j) {
                const int e = kf * 8 + j;
                h[j] = fmaxf(0.f,
                             fmaf(pos, w1a[e], fmaf(fwd, w1b[e], b1v[e])));
            }
            union { half8 v; half2v p[4]; } uh, ul;
            #pragma unroll
            for (int p = 0; p < 4; ++p)
                uh.p[p] = pkrtz(h[2 * p], h[2 * p + 1]);
            #pragma unroll
            for (int p = 0; p < 4; ++p) {
                const float r0 =
                    (h[2 * p]     - (float)uh.p[p][0]) * 4096.0f;
                const float r1 =
                    (h[2 * p + 1] - (float)uh.p[p][1]) * 4096.0f;
                ul.p[p] = pkrtz(r0, r1);
            }
            Hh[kf] = uh.v;
            Hl[kf] = ul.v;
        }

        // ---- layer 2: h2^T[n][m] = W2^T @ h1^T via MFMA ----
        // accA = b2 + wh*hh ; accB = wl*hh + wh*hl (scale 4096)
        float4v accA[4], accB[4];
        #pragma unroll
        for (int t = 0; t < 4; ++t) {
            accB[t] = __builtin_amdgcn_mfma_f32_16x16x32_f16(
                Wl[0][t], Hh[0], zf, 0, 0, 0);
            accB[t] = __builtin_amdgcn_mfma_f32_16x16x32_f16(
                Wh[0][t], Hl[0], accB[t], 0, 0, 0);
            accB[t] = __builtin_amdgcn_mfma_f32_16x16x32_f16(
                Wl[1][t], Hh[1], accB[t], 0, 0, 0);
            accB[t] = __builtin_amdgcn_mfma_f32_16x16x32_f16(
                Wh[1][t], Hl[1], accB[t], 0, 0, 0);
            accA[t] = __builtin_amdgcn_mfma_f32_16x16x32_f16(
                Wh[0][t], Hh[0], b2f[t], 0, 0, 0);
            accA[t] = __builtin_amdgcn_mfma_f32_16x16x32_f16(
                Wh[1][t], Hh[1], accA[t], 0, 0, 0);
        }

        // ---- layer 3: partials over my 16 n-values (all for row lanelo) ----
        float s0 = 0.f, s1 = 0.f, s2 = 0.f;
        #pragma unroll
        for (int t = 0; t < 4; ++t) {
            #pragma unroll
            for (int r = 0; r < 4; ++r) {
                float h2 = fmaf(accB[t][r], 1.0f / 4096.0f, accA[t][r]);
                h2 = fmaxf(h2, 0.f);
                s0 = fmaf(h2, w3v[t][r][0], s0);
                s1 = fmaf(h2, w3v[t][r][1], s1);
                s2 = fmaf(h2, w3v[t][r][2], s2);
            }
        }
        // ---- 2-stage cross-replica reduce; replicas end bit-identical ----
        s0 += swz_xor16(s0);
        s1 += swz_xor16(s1);
        s2 += swz_xor16(s2);
        s0 += __shfl_xor(s0, 32, 64);
        s1 += __shfl_xor(s1, 32, 64);
        s2 += __shfl_xor(s2, 32, 64);
        l0 = s0 + b3v0;
        l1 = s1 + b3v1;
        l2 = s2 + b3v2;

        // ---- argmax (first-max-wins); sigmoid monotone -> logits suffice ----
        const float m01   = fmaxf(l0, l1);
        const float delta = (l2 > m01) ? 1.0f : ((l1 > l0) ? 0.0f : -1.0f);
        pos += delta;
        fwd += 1.0f;
    }

    // ---- epilogue: every lane has its row's logits; q8==0 lanes store ----
    if (q8 == 0 && myRow < B) {
        const float p0 = 1.f / (1.f + __expf(-l0));
        const float p1 = 1.f / (1.f + __expf(-l1));
        const float p2 = 1.f / (1.f + __expf(-l2));
        float2* o = (float2*)(out + (size_t)myRow * 6);
        o[0] = make_float2(pos, fwd);
        o[1] = make_float2(p0, p1);
        o[2] = make_float2(p2, c5 + (float)NSTEPS);
    }
}

extern "C" void kernel_launch(void* const* d_in, const int* in_sizes, int n_in,
                              void* d_out, int out_size, void* d_ws, size_t ws_size,
                              hipStream_t stream) {
    const float* x  = (const float*)d_in[0];
    const float* W1 = (const float*)d_in[1];
    const float* b1 = (const float*)d_in[2];
    const float* W2 = (const float*)d_in[3];
    const float* b2 = (const float*)d_in[4];
    const float* W3 = (const float*)d_in[5];
    const float* b3 = (const float*)d_in[6];
    float* out = (float*)d_out;

    const int B = in_sizes[0] / 6;              // 1048576
    const int nBlocks = (B + 63) / 64;          // 64 rows/block (4 waves x 16)

    program_kernel<<<nBlocks, 256, 0, stream>>>(
        x, W1, b1, W2, b2, W3, b3, out, B);
}

// Round 7
// 659.277 us; speedup vs baseline: 5.8199x; 1.0408x over previous
//
#include <hip/hip_runtime.h>
#include <math.h>

// Program interpreter: B=1M rows, 19 steps of MLP(2->64->64->3) + argmax walk.
// fp32 emulated on f16 MFMA, 2-limb splits (lo limb scaled 2^12, RTZ pack).
//
// R7: latency-bound fix. Two independent 16-row tiles per wave (2x ILP per
// wave ~= 4-wave latency hiding at 2 waves/SIMD). The q8-uniform tables
// (w1a/w1b/b1, W3, ~96 VGPRs in R6) move to tiny LDS tables read as 16-lane
// broadcasts. Layer-3 partial sums tree-ified (depth 16 -> 6). W2 limb frags
// (A-operands) + b2 C-frags stay in registers, shared by both tiles.

#define NSTEPS 19

typedef _Float16 half8  __attribute__((ext_vector_type(8)));
typedef _Float16 half2v __attribute__((ext_vector_type(2)));
typedef float    float4v __attribute__((ext_vector_type(4)));

__device__ __forceinline__ half2v pkrtz(float a, float b) {
    return __builtin_bit_cast(half2v, __builtin_amdgcn_cvt_pkrtz(a, b));
}

__device__ __forceinline__ float swz_xor16(float v) {
    // BitMode: and=0x1F, or=0, xor=16 -> lane' = lane ^ 16 (within 32-group)
    int r = __builtin_amdgcn_ds_swizzle(__builtin_bit_cast(int, v), 0x401F);
    return __builtin_bit_cast(float, r);
}

__global__ __launch_bounds__(256, 2)
void program_kernel(const float* __restrict__ x,
                    const float* __restrict__ W1,
                    const float* __restrict__ b1,
                    const float* __restrict__ W2,
                    const float* __restrict__ b2,
                    const float* __restrict__ W3,
                    const float* __restrict__ b3,
                    float* __restrict__ out,
                    int B) {
    const int tid    = threadIdx.x;
    const int lane   = tid & 63;
    const int wave   = tid >> 6;
    const int lanelo = lane & 15;   // m: batch row within a tile
    const int q8     = lane >> 4;   // k-slice / replica group 0..3

    // ---- LDS tables (q8-uniform data; 16-lane broadcast reads) ----
    // w1t: chunks 0-3 = w1a, 4-7 = w1b, 8-11 = b1; element e=4c..4c+3 of a
    // lane's k-slice, k = (c>>1)*32 + q8*8 + (c&1)*4 + i.
    // w3t[t*3+cc][q8] = { W3[(16t+4*q8+r)*3+cc], r=0..3 }.
    __shared__ float4v w1t[12][4];
    __shared__ float4v w3t[12][4];
    for (int idx = tid; idx < 96; idx += 256) {
        if (idx < 48) {
            const int table = idx >> 4;          // 0=w1a,1=w1b,2=b1
            const int rem   = idx & 15;
            const int q = rem >> 2, c = rem & 3;
            const int k0 = q * 8 + (c & 1) * 4 + (c >> 1) * 32;
            const float* src = (table == 0) ? (W1 + k0)
                             : (table == 1) ? (W1 + 64 + k0)
                                            : (b1 + k0);
            w1t[table * 4 + c][q] = (float4v){src[0], src[1], src[2], src[3]};
        } else {
            const int j = idx - 48;
            const int t = j / 12, rem = j % 12;
            const int cc = rem >> 2, q = rem & 3;
            const int n0 = 16 * t + 4 * q;
            w3t[t * 3 + cc][q] =
                (float4v){W3[(n0 + 0) * 3 + cc], W3[(n0 + 1) * 3 + cc],
                          W3[(n0 + 2) * 3 + cc], W3[(n0 + 3) * 3 + cc]};
        }
    }
    __syncthreads();

    // ---- W2^T limb A-frags (shared by both tiles) ----
    half8 Wh[2][4], Wl[2][4];
    #pragma unroll
    for (int kf = 0; kf < 2; ++kf) {
        #pragma unroll
        for (int t = 0; t < 4; ++t) {
            half8 bh, bl;
            #pragma unroll
            for (int j = 0; j < 8; ++j) {
                const float w =
                    W2[(kf * 32 + q8 * 8 + j) * 64 + t * 16 + lanelo];
                const _Float16 wh = (_Float16)w;                       // RNE
                const _Float16 wl = (_Float16)((w - (float)wh) * 4096.0f);
                bh[j] = wh;
                bl[j] = wl;
            }
            Wh[kf][t] = bh;
            Wl[kf][t] = bl;
        }
    }

    // ---- b2 C-init frags (q8-dependent, shared by both tiles) ----
    float4v b2f[4];
    #pragma unroll
    for (int t = 0; t < 4; ++t) {
        const int n = t * 16 + q8 * 4;
        b2f[t] = (float4v){b2[n], b2[n + 1], b2[n + 2], b2[n + 3]};
    }
    const float b3v0 = b3[0], b3v1 = b3[1], b3v2 = b3[2];

    // ---- two tiles of 16 rows each ----
    const int rowBase = blockIdx.x * 128 + wave * 32;
    const int row0 = rowBase + lanelo;
    const int row1 = rowBase + 16 + lanelo;
    const int ld0 = row0 < B ? row0 : (B - 1);
    const int ld1 = row1 < B ? row1 : (B - 1);

    float pos[2], fwd[2], c5[2], l0[2], l1[2], l2[2];
    {
        const float* r = x + (size_t)ld0 * 6;
        pos[0] = r[0]; fwd[0] = r[1]; c5[0] = r[5];
        const float* s = x + (size_t)ld1 * 6;
        pos[1] = s[0]; fwd[1] = s[1]; c5[1] = s[5];
    }
    l0[0] = l0[1] = l1[0] = l1[1] = l2[0] = l2[1] = 0.f;

    const float4v zf = {0.f, 0.f, 0.f, 0.f};

    #pragma unroll 1
    for (int step = 0; step < NSTEPS; ++step) {
        // ---- layer 1 + 2-limb split, both tiles ----
        half8 Hh[2][2], Hl[2][2];   // [tile][kf]
        #pragma unroll
        for (int kf = 0; kf < 2; ++kf) {
            float4v wa0 = w1t[kf * 2 + 0][q8], wa1 = w1t[kf * 2 + 1][q8];
            float4v wb0 = w1t[4 + kf * 2 + 0][q8], wb1 = w1t[4 + kf * 2 + 1][q8];
            float4v bb0 = w1t[8 + kf * 2 + 0][q8], bb1 = w1t[8 + kf * 2 + 1][q8];
            #pragma unroll
            for (int u = 0; u < 2; ++u) {
                float h[8];
                #pragma unroll
                for (int i = 0; i < 4; ++i) {
                    h[i] = fmaxf(0.f,
                        fmaf(pos[u], wa0[i], fmaf(fwd[u], wb0[i], bb0[i])));
                    h[4 + i] = fmaxf(0.f,
                        fmaf(pos[u], wa1[i], fmaf(fwd[u], wb1[i], bb1[i])));
                }
                union { half8 v; half2v p[4]; } uh, ul;
                #pragma unroll
                for (int p = 0; p < 4; ++p)
                    uh.p[p] = pkrtz(h[2 * p], h[2 * p + 1]);
                #pragma unroll
                for (int p = 0; p < 4; ++p) {
                    const float r0 = (h[2 * p]     - (float)uh.p[p][0]) * 4096.0f;
                    const float r1 = (h[2 * p + 1] - (float)uh.p[p][1]) * 4096.0f;
                    ul.p[p] = pkrtz(r0, r1);
                }
                Hh[u][kf] = uh.v;
                Hl[u][kf] = ul.v;
            }
        }

        // ---- layer 2 via MFMA, both tiles (independent chains) ----
        float4v accA[2][4], accB[2][4];
        #pragma unroll
        for (int u = 0; u < 2; ++u) {
            #pragma unroll
            for (int t = 0; t < 4; ++t) {
                accB[u][t] = __builtin_amdgcn_mfma_f32_16x16x32_f16(
                    Wl[0][t], Hh[u][0], zf, 0, 0, 0);
                accB[u][t] = __builtin_amdgcn_mfma_f32_16x16x32_f16(
                    Wh[0][t], Hl[u][0], accB[u][t], 0, 0, 0);
                accB[u][t] = __builtin_amdgcn_mfma_f32_16x16x32_f16(
                    Wl[1][t], Hh[u][1], accB[u][t], 0, 0, 0);
                accB[u][t] = __builtin_amdgcn_mfma_f32_16x16x32_f16(
                    Wh[1][t], Hl[u][1], accB[u][t], 0, 0, 0);
                accA[u][t] = __builtin_amdgcn_mfma_f32_16x16x32_f16(
                    Wh[0][t], Hh[u][0], b2f[t], 0, 0, 0);
                accA[u][t] = __builtin_amdgcn_mfma_f32_16x16x32_f16(
                    Wh[1][t], Hh[u][1], accA[u][t], 0, 0, 0);
            }
        }

        // ---- layer 3 (tree) + cross-replica reduce + argmax, both tiles ----
        #pragma unroll
        for (int u = 0; u < 2; ++u) {
            float4v h2[4];
            #pragma unroll
            for (int t = 0; t < 4; ++t) {
                #pragma unroll
                for (int r = 0; r < 4; ++r) {
                    float v = fmaf(accB[u][t][r], 1.0f / 4096.0f, accA[u][t][r]);
                    h2[t][r] = fmaxf(v, 0.f);
                }
            }
            float s[3];
            #pragma unroll
            for (int c = 0; c < 3; ++c) {
                float d[4];
                #pragma unroll
                for (int t = 0; t < 4; ++t) {
                    const float4v w = w3t[t * 3 + c][q8];
                    float a = h2[t][0] * w[0];
                    a = fmaf(h2[t][1], w[1], a);
                    a = fmaf(h2[t][2], w[2], a);
                    a = fmaf(h2[t][3], w[3], a);
                    d[t] = a;
                }
                s[c] = (d[0] + d[1]) + (d[2] + d[3]);
            }
            s[0] += swz_xor16(s[0]);
            s[1] += swz_xor16(s[1]);
            s[2] += swz_xor16(s[2]);
            s[0] += __shfl_xor(s[0], 32, 64);
            s[1] += __shfl_xor(s[1], 32, 64);
            s[2] += __shfl_xor(s[2], 32, 64);
            l0[u] = s[0] + b3v0;
            l1[u] = s[1] + b3v1;
            l2[u] = s[2] + b3v2;

            // argmax, first-max-wins; sigmoid monotone -> logits suffice
            const float m01 = fmaxf(l0[u], l1[u]);
            const float delta =
                (l2[u] > m01) ? 1.0f : ((l1[u] > l0[u]) ? 0.0f : -1.0f);
            pos[u] += delta;
            fwd[u] += 1.0f;
        }
    }

    // ---- epilogue: q8==0 lanes hold valid state for both tiles ----
    if (q8 == 0) {
        if (row0 < B) {
            const float p0 = 1.f / (1.f + __expf(-l0[0]));
            const float p1 = 1.f / (1.f + __expf(-l1[0]));
            const float p2 = 1.f / (1.f + __expf(-l2[0]));
            float2* o = (float2*)(out + (size_t)row0 * 6);
            o[0] = make_float2(pos[0], fwd[0]);
            o[1] = make_float2(p0, p1);
            o[2] = make_float2(p2, c5[0] + (float)NSTEPS);
        }
        if (row1 < B) {
            const float p0 = 1.f / (1.f + __expf(-l0[1]));
            const float p1 = 1.f / (1.f + __expf(-l1[1]));
            const float p2 = 1.f / (1.f + __expf(-l2[1]));
            float2* o = (float2*)(out + (size_t)row1 * 6);
            o[0] = make_float2(pos[1], fwd[1]);
            o[1] = make_float2(p0, p1);
            o[2] = make_float2(p2, c5[1] + (float)NSTEPS);
        }
    }
}

extern "C" void kernel_launch(void* const* d_in, const int* in_sizes, int n_in,
                              void* d_out, int out_size, void* d_ws, size_t ws_size,
                              hipStream_t stream) {
    const float* x  = (const float*)d_in[0];
    const float* W1 = (const float*)d_in[1];
    const float* b1 = (const float*)d_in[2];
    const float* W2 = (const float*)d_in[3];
    const float* b2 = (const float*)d_in[4];
    const float* W3 = (const float*)d_in[5];
    const float* b3 = (const float*)d_in[6];
    float* out = (float*)d_out;

    const int B = in_sizes[0] / 6;              // 1048576
    const int nBlocks = (B + 127) / 128;        // 128 rows/block (4 waves x 32)

    program_kernel<<<nBlocks, 256, 0, stream>>>(
        x, W1, b1, W2, b2, W3, b3, out, B);
}

// Round 8
// 637.075 us; speedup vs baseline: 6.0227x; 1.0348x over previous
//
#include <hip/hip_runtime.h>
#include <math.h>

// Program interpreter: B=1M rows, 19 steps of MLP(2->64->64->3) + argmax walk.
// fp32 emulated on f16 MFMA, 2-limb splits (lo limb scaled 2^12, RTZ pack).
//
// R8: instruction-stream diet. One 16-row tile/wave. No LDS tables (DS pipe
// was 2x oversubscribed in R7); w1 tables live in VGPRs, W2 limb frags /
// b2 C-frags / accumulators are MFMA-only (AGPR-eligible, never VALU-read
// except the h2 combine). Bulk math on float2 vectors -> v_pk_fma_f32 /
// v_pk_max_f32 (gfx950 packed fp32, 2 elem/inst). Per-step decision uses two
// difference-dots (w3_1 - w3_0, w3_2 - w3_0): sign(l1-l0), sign(l2-l0/l1)
// are all the walk needs; full logits reconstructed at the last step only.

#define NSTEPS 19

typedef _Float16 half8   __attribute__((ext_vector_type(8)));
typedef _Float16 half2v  __attribute__((ext_vector_type(2)));
typedef float    float2v __attribute__((ext_vector_type(2)));
typedef float    float4v __attribute__((ext_vector_type(4)));

__device__ __forceinline__ half2v pkrtz(float a, float b) {
    return __builtin_bit_cast(half2v, __builtin_amdgcn_cvt_pkrtz(a, b));
}
__device__ __forceinline__ float swz_xor16(float v) {
    // BitMode: and=0x1F, or=0, xor=16 -> lane' = lane ^ 16 (within 32-group)
    int r = __builtin_amdgcn_ds_swizzle(__builtin_bit_cast(int, v), 0x401F);
    return __builtin_bit_cast(float, r);
}
__device__ __forceinline__ float2v lo2(float4v v) {
    return __builtin_shufflevector(v, v, 0, 1);
}
__device__ __forceinline__ float2v hi2(float4v v) {
    return __builtin_shufflevector(v, v, 2, 3);
}

__global__ __launch_bounds__(256, 2)
void program_kernel(const float* __restrict__ x,
                    const float* __restrict__ W1,
                    const float* __restrict__ b1,
                    const float* __restrict__ W2,
                    const float* __restrict__ b2,
                    const float* __restrict__ W3,
                    const float* __restrict__ b3,
                    float* __restrict__ out,
                    int B) {
    const int tid    = threadIdx.x;
    const int lane   = tid & 63;
    const int wave   = tid >> 6;
    const int lanelo = lane & 15;   // m: my batch row within the tile
    const int q8     = lane >> 4;   // k-slice / replica group 0..3
    const int myRow  = blockIdx.x * 64 + wave * 16 + lanelo;
    const int rowLd  = myRow < B ? myRow : (B - 1);

    // ---- w1 tables as pairs (VGPR): pair i of kf-half: k = kf*32+q8*8+2i ----
    float2v w1a[8], w1b[8], b1v[8];
    #pragma unroll
    for (int kf = 0; kf < 2; ++kf) {
        const int k0 = kf * 32 + q8 * 8;
        const float2v* a = (const float2v*)(W1 + k0);
        const float2v* bb = (const float2v*)(W1 + 64 + k0);
        const float2v* bv = (const float2v*)(b1 + k0);
        #pragma unroll
        for (int i = 0; i < 4; ++i) {
            w1a[kf * 4 + i] = a[i];
            w1b[kf * 4 + i] = bb[i];
            b1v[kf * 4 + i] = bv[i];
        }
    }

    // ---- W2^T limb A-frags (MFMA-only; AGPR-eligible) ----
    half8 Wh[2][4], Wl[2][4];
    #pragma unroll
    for (int kf = 0; kf < 2; ++kf) {
        #pragma unroll
        for (int t = 0; t < 4; ++t) {
            half8 bh, bl;
            #pragma unroll
            for (int j = 0; j < 8; ++j) {
                const float w =
                    W2[(kf * 32 + q8 * 8 + j) * 64 + t * 16 + lanelo];
                const _Float16 wh = (_Float16)w;                       // RNE
                const _Float16 wl = (_Float16)((w - (float)wh) * 4096.0f);
                bh[j] = wh;
                bl[j] = wl;
            }
            Wh[kf][t] = bh;
            Wl[kf][t] = bl;
        }
    }

    // ---- b2 C-init frags (MFMA-C only) ----
    float4v b2f[4];
    #pragma unroll
    for (int t = 0; t < 4; ++t) {
        const int n = t * 16 + q8 * 4;
        b2f[t] = (float4v){b2[n], b2[n + 1], b2[n + 2], b2[n + 3]};
    }

    // ---- W3 difference tables (VGPR): my n-set n = 16t+4*q8+r, pairs ----
    float2v d10[8], d20[8];
    #pragma unroll
    for (int p = 0; p < 8; ++p) {
        const int n0 = (p >> 1) * 16 + q8 * 4 + (p & 1) * 2;
        const float w00 = W3[n0 * 3 + 0],       w01 = W3[n0 * 3 + 1];
        const float w02 = W3[n0 * 3 + 2];
        const float w10 = W3[(n0 + 1) * 3 + 0], w11 = W3[(n0 + 1) * 3 + 1];
        const float w12 = W3[(n0 + 1) * 3 + 2];
        d10[p] = (float2v){w01 - w00, w11 - w10};
        d20[p] = (float2v){w02 - w00, w12 - w10};
    }
    const float b3v0 = b3[0];
    const float db10 = b3[1] - b3[0];
    const float db20 = b3[2] - b3[0];

    // ---- initial row state (4x replicated across q8 groups) ----
    float pos, fwd, c5;
    {
        const float* xr = x + (size_t)rowLd * 6;
        pos = xr[0];
        fwd = xr[1];
        c5  = xr[5];
    }

    const float4v zf = {0.f, 0.f, 0.f, 0.f};
    const float2v z2 = {0.f, 0.f};
    const float2v kinv = {1.0f / 4096.0f, 1.0f / 4096.0f};
    float l0 = 0.f, l1 = 0.f, l2 = 0.f;

    #pragma unroll 1
    for (int step = 0; step < NSTEPS; ++step) {
        // ---- layer 1 (packed) + 2-limb split -> B-frag limbs ----
        const float2v posp = {pos, pos}, fwdp = {fwd, fwd};
        half8 Hh[2], Hl[2];
        #pragma unroll
        for (int kf = 0; kf < 2; ++kf) {
            union { half8 v; half2v h2[4]; } uh, ul;
            #pragma unroll
            for (int p = 0; p < 4; ++p) {
                const int e = kf * 4 + p;
                float2v z = __builtin_elementwise_fma(fwdp, w1b[e], b1v[e]);
                z = __builtin_elementwise_fma(posp, w1a[e], z);
                const float2v hp = __builtin_elementwise_max(z, z2);
                uh.h2[p] = pkrtz(hp[0], hp[1]);
                // residuals (hi-half f16 extract folds into v_fma_mix)
                const float r0 = fmaf((float)uh.h2[p][0], -1.0f, hp[0]);
                const float r1 = fmaf((float)uh.h2[p][1], -1.0f, hp[1]);
                const float2v rp = (float2v){r0, r1} * 4096.0f;  // pk_mul
                ul.h2[p] = pkrtz(rp[0], rp[1]);
            }
            Hh[kf] = uh.v;
            Hl[kf] = ul.v;
        }

        // ---- layer 2 via MFMA (same chain/order as R6/R7) ----
        float4v accA[4], accB[4];
        #pragma unroll
        for (int t = 0; t < 4; ++t) {
            accB[t] = __builtin_amdgcn_mfma_f32_16x16x32_f16(
                Wl[0][t], Hh[0], zf, 0, 0, 0);
            accB[t] = __builtin_amdgcn_mfma_f32_16x16x32_f16(
                Wh[0][t], Hl[0], accB[t], 0, 0, 0);
            accB[t] = __builtin_amdgcn_mfma_f32_16x16x32_f16(
                Wl[1][t], Hh[1], accB[t], 0, 0, 0);
            accB[t] = __builtin_amdgcn_mfma_f32_16x16x32_f16(
                Wh[1][t], Hl[1], accB[t], 0, 0, 0);
            accA[t] = __builtin_amdgcn_mfma_f32_16x16x32_f16(
                Wh[0][t], Hh[0], b2f[t], 0, 0, 0);
            accA[t] = __builtin_amdgcn_mfma_f32_16x16x32_f16(
                Wh[1][t], Hh[1], accA[t], 0, 0, 0);
        }

        // ---- h2 (packed combine+relu) ----
        float2v h2p[8];
        #pragma unroll
        for (int t = 0; t < 4; ++t) {
            h2p[2 * t] = __builtin_elementwise_max(
                __builtin_elementwise_fma(lo2(accB[t]), kinv, lo2(accA[t])),
                z2);
            h2p[2 * t + 1] = __builtin_elementwise_max(
                __builtin_elementwise_fma(hi2(accB[t]), kinv, hi2(accA[t])),
                z2);
        }

        // ---- difference dots (packed) + cross-replica reduce ----
        float2v s1 = z2, s2 = z2;
        #pragma unroll
        for (int p = 0; p < 8; ++p) {
            s1 = __builtin_elementwise_fma(h2p[p], d10[p], s1);
            s2 = __builtin_elementwise_fma(h2p[p], d20[p], s2);
        }
        float g10 = s1[0] + s1[1];
        float g20 = s2[0] + s2[1];
        g10 += swz_xor16(g10);
        g20 += swz_xor16(g20);
        g10 += __shfl_xor(g10, 32, 64);
        g20 += __shfl_xor(g20, 32, 64);
        g10 += db10;   // = l1 - l0
        g20 += db20;   // = l2 - l0

        // ---- last step: reconstruct full logits for the output probs ----
        if (step == NSTEPS - 1) {
            float2v s0 = z2;
            #pragma unroll
            for (int p = 0; p < 8; ++p) {
                const int n0 = (p >> 1) * 16 + q8 * 4 + (p & 1) * 2;
                const float2v w30 = {W3[n0 * 3], W3[(n0 + 1) * 3]};
                s0 = __builtin_elementwise_fma(h2p[p], w30, s0);
            }
            float t0 = s0[0] + s0[1];
            t0 += swz_xor16(t0);
            t0 += __shfl_xor(t0, 32, 64);
            l0 = t0 + b3v0;
            l1 = l0 + g10;
            l2 = l0 + g20;
        }

        // ---- decision: l2 > max(l0,l1) <=> g20 > max(0,g10);
        //      l1 > l0 <=> g10 > 0 (first-max-wins preserved) ----
        const float delta =
            (g20 > fmaxf(0.f, g10)) ? 1.0f : ((g10 > 0.f) ? 0.0f : -1.0f);
        pos += delta;
        fwd += 1.0f;
    }

    // ---- epilogue: all lanes have their row's logits; q8==0 stores ----
    if (q8 == 0 && myRow < B) {
        const float p0 = 1.f / (1.f + __expf(-l0));
        const float p1 = 1.f / (1.f + __expf(-l1));
        const float p2 = 1.f / (1.f + __expf(-l2));
        float2* o = (float2*)(out + (size_t)myRow * 6);
        o[0] = make_float2(pos, fwd);
        o[1] = make_float2(p0, p1);
        o[2] = make_float2(p2, c5 + (float)NSTEPS);
    }
}

extern "C" void kernel_launch(void* const* d_in, const int* in_sizes, int n_in,
                              void* d_out, int out_size, void* d_ws, size_t ws_size,
                              hipStream_t stream) {
    const float* x  = (const float*)d_in[0];
    const float* W1 = (const float*)d_in[1];
    const float* b1 = (const float*)d_in[2];
    const float* W2 = (const float*)d_in[3];
    const float* b2 = (const float*)d_in[4];
    const float* W3 = (const float*)d_in[5];
    const float* b3 = (const float*)d_in[6];
    float* out = (float*)d_out;

    const int B = in_sizes[0] / 6;              // 1048576
    const int nBlocks = (B + 63) / 64;          // 64 rows/block (4 waves x 16)

    program_kernel<<<nBlocks, 256, 0, stream>>>(
        x, W1, b1, W2, b2, W3, b3, out, B);
}